// Round 1
// baseline (372.018 us; speedup 1.0000x reference)
//
#include <hip/hip_runtime.h>
#include <math.h>

#define HDIM 60
#define EPSC 0.01f
#define ALPHAC 0.1f

// ---------------------------------------------------------------------------
// Kernel 1: compute h_0 = ICNN(Xref) once into workspace (single tiny block).
// ---------------------------------------------------------------------------
__global__ void dho_h0_kernel(const float* __restrict__ Xref,
                              const float* __restrict__ W1, const float* __restrict__ b1,
                              const float* __restrict__ W2, const float* __restrict__ b2,
                              const float* __restrict__ W3, const float* __restrict__ b3,
                              const float* __restrict__ Wim2, const float* __restrict__ Wim3,
                              float* __restrict__ h0out)
{
    __shared__ float z1s[HDIM];
    __shared__ float z2s[HDIM];
    const int t = threadIdx.x;
    const float x0 = Xref[0], x1 = Xref[1];
    if (t < HDIM) {
        float a = W1[2 * t] * x0 + W1[2 * t + 1] * x1 + b1[t];
        float e = expf(-fabsf(a));
        z1s[t] = logf(1.0f + e) + fmaxf(a, 0.0f);
    }
    __syncthreads();
    if (t < HDIM) {
        float a = b2[t] + Wim2[2 * t] * x0 + Wim2[2 * t + 1] * x1;
        for (int i = 0; i < HDIM; ++i) a += W2[t * HDIM + i] * z1s[i];
        float e = expf(-fabsf(a));
        z2s[t] = logf(1.0f + e) + fmaxf(a, 0.0f);
    }
    __syncthreads();
    if (t == 0) {
        float a = b3[0] + Wim3[0] * x0 + Wim3[1] * x1;
        for (int j = 0; j < HDIM; ++j) a += W3[j] * z2s[j];
        float e = expf(-fabsf(a));
        h0out[0] = logf(1.0f + e) + fmaxf(a, 0.0f);
    }
}

// ---------------------------------------------------------------------------
// Kernel 2: per-sample fused forward + analytic gradient + correction.
// One thread = one sample. Weights staged in LDS; W2 row held in registers
// and used for BOTH the forward FMA (a2) and the reverse-mode FMA (g1).
// ---------------------------------------------------------------------------
__global__ __launch_bounds__(256) void dho_main_kernel(
    const float* __restrict__ X, const float* __restrict__ U,
    const float* __restrict__ W1, const float* __restrict__ b1,
    const float* __restrict__ W2, const float* __restrict__ b2,
    const float* __restrict__ W3,
    const float* __restrict__ Wim2,
    const float* __restrict__ misc,   // staged by kernel_launch? no: loaded here from individual ptrs
    const float* __restrict__ W_fnn, const float* __restrict__ W_gnn,
    const float* __restrict__ b_gnn, const float* __restrict__ b3,
    const float* __restrict__ Wim3, const float* __restrict__ Xref,
    const float* __restrict__ h0p,
    float* __restrict__ out, int N)
{
    __shared__ __align__(16) float sW2[HDIM * HDIM];
    __shared__ float sW1[HDIM * 2];
    __shared__ float sb1[HDIM];
    __shared__ float sb2[HDIM];
    __shared__ float sW3[HDIM];
    __shared__ float sWim2[HDIM * 2];
    __shared__ float sM[16];

    const int t = threadIdx.x;
    for (int k = t; k < HDIM * HDIM; k += 256) sW2[k] = W2[k];
    if (t < HDIM) {
        sW1[2 * t]     = W1[2 * t];
        sW1[2 * t + 1] = W1[2 * t + 1];
        sb1[t]  = b1[t];
        sb2[t]  = b2[t];
        sW3[t]  = W3[t];
        sWim2[2 * t]     = Wim2[2 * t];
        sWim2[2 * t + 1] = Wim2[2 * t + 1];
    }
    if (t == 0) {
        sM[0] = W_fnn[0]; sM[1] = W_fnn[1]; sM[2] = W_fnn[2]; sM[3] = W_fnn[3];
        sM[4] = W_gnn[0]; sM[5] = W_gnn[1]; sM[6] = W_gnn[2]; sM[7] = W_gnn[3];
        sM[8] = b_gnn[0]; sM[9] = b_gnn[1];
        sM[10] = Wim3[0]; sM[11] = Wim3[1];
        sM[12] = b3[0];
        sM[13] = Xref[0]; sM[14] = Xref[1];
        sM[15] = h0p[0];
    }
    __syncthreads();

    const int n = blockIdx.x * 256 + t;
    if (n >= N) return;

    const float2 x = ((const float2*)X)[n];

    // ---- layer 1: z1 = softplus(W1 x + b1) ----
    float z1[HDIM];
#pragma unroll
    for (int i = 0; i < HDIM; ++i) {
        float a = sW1[2 * i] * x.x + sW1[2 * i + 1] * x.y + sb1[i];
        float e = expf(-fabsf(a));
        z1[i] = logf(1.0f + e) + fmaxf(a, 0.0f);
    }

    // ---- layer 2 forward + reverse-mode accumulation (single pass over W2) ----
    float g1acc[HDIM];
#pragma unroll
    for (int i = 0; i < HDIM; ++i) g1acc[i] = 0.0f;

    float a3acc = 0.0f, q0 = 0.0f, q1 = 0.0f;

#pragma unroll 1
    for (int j = 0; j < HDIM; ++j) {
        const float4* rp = (const float4*)(&sW2[j * HDIM]);
        float4 r[15];
#pragma unroll
        for (int c = 0; c < 15; ++c) r[c] = rp[c];

        float acc0 = 0.0f, acc1 = 0.0f, acc2 = 0.0f, acc3 = 0.0f;
#pragma unroll
        for (int c = 0; c < 15; ++c) {
            acc0 += r[c].x * z1[4 * c + 0];
            acc1 += r[c].y * z1[4 * c + 1];
            acc2 += r[c].z * z1[4 * c + 2];
            acc3 += r[c].w * z1[4 * c + 3];
        }
        float wi0 = sWim2[2 * j], wi1 = sWim2[2 * j + 1];
        float a2 = (acc0 + acc1) + (acc2 + acc3) + sb2[j] + wi0 * x.x + wi1 * x.y;

        float e   = expf(-fabsf(a2));
        float inv = 1.0f / (1.0f + e);
        float z2  = logf(1.0f + e) + fmaxf(a2, 0.0f);
        float s2  = (a2 >= 0.0f ? 1.0f : e) * inv;

        float w3j = sW3[j];
        a3acc += w3j * z2;
        float tj = w3j * s2;
        q0 += tj * wi0;
        q1 += tj * wi1;
#pragma unroll
        for (int c = 0; c < 15; ++c) {
            g1acc[4 * c + 0] += tj * r[c].x;
            g1acc[4 * c + 1] += tj * r[c].y;
            g1acc[4 * c + 2] += tj * r[c].z;
            g1acc[4 * c + 3] += tj * r[c].w;
        }
    }

    // ---- output layer ----
    const float wim3_0 = sM[10], wim3_1 = sM[11];
    float a3 = a3acc + sM[12] + wim3_0 * x.x + wim3_1 * x.y;
    float e3   = expf(-fabsf(a3));
    float inv3 = 1.0f / (1.0f + e3);
    float hX   = logf(1.0f + e3) + fmaxf(a3, 0.0f);
    float s3   = (a3 >= 0.0f ? 1.0f : e3) * inv3;

    float h = hX - sM[15];
    float sigma, sigp;
    if (h >= 1.0f)      { sigma = h - 0.5f;     sigp = 1.0f; }
    else if (h > 0.0f)  { sigma = 0.5f * h * h; sigp = h;    }
    else                { sigma = 0.0f;         sigp = 0.0f; }

    float dx0 = x.x - sM[13], dx1 = x.y - sM[14];
    float V = sigma + EPSC * (dx0 * dx0 + dx1 * dx1);

    // ---- backprop through layer 1: dh/dx = s3*(Wim3 + q + sum_i g1*s1*W1[i]) ----
    float sum0 = 0.0f, sum1 = 0.0f;
#pragma unroll
    for (int i = 0; i < HDIM; ++i) {
        float s1 = 1.0f - expf(-z1[i]);   // sigmoid(a1) = 1 - exp(-softplus(a1))
        float c  = g1acc[i] * s1;
        sum0 += c * sW1[2 * i];
        sum1 += c * sW1[2 * i + 1];
    }
    float dh0 = s3 * (wim3_0 + q0 + sum0);
    float dh1 = s3 * (wim3_1 + q1 + sum1);

    float dV0 = sigp * dh0 + 2.0f * EPSC * dx0;
    float dV1 = sigp * dh1 + 2.0f * EPSC * dx1;

    // ---- dynamics + correction ----
    float f0 = sM[0] * x.x + sM[1] * x.y;
    float f1 = sM[2] * x.x + sM[3] * x.y;
    float gg0 = sM[4] * x.x + sM[5] * x.y + sM[8];
    float gg1 = sM[6] * x.x + sM[7] * x.y + sM[9];

    float sc = dV0 * f0 + dV1 * f1 + ALPHAC * V - fabsf(dV0 * gg0 + dV1 * gg1);
    float nrm = dV0 * dV0 + dV1 * dV1;
    float rr  = fmaxf(sc, 0.0f) / nrm;

    float u = U[n];
    float o0 = f0 - dV0 * rr + gg0 * u;
    float o1 = f1 - dV1 * rr + gg1 * u;
    ((float2*)out)[n] = make_float2(o0, o1);
}

extern "C" void kernel_launch(void* const* d_in, const int* in_sizes, int n_in,
                              void* d_out, int out_size, void* d_ws, size_t ws_size,
                              hipStream_t stream) {
    // setup_inputs order:
    // 0:X 1:U 2:Xref 3:W_fnn 4:W_gnn 5:b_gnn 6:W1 7:b1 8:W2 9:b2 10:W3 11:b3 12:Wim2 13:Wim3
    const float* X     = (const float*)d_in[0];
    const float* U     = (const float*)d_in[1];
    const float* Xref  = (const float*)d_in[2];
    const float* W_fnn = (const float*)d_in[3];
    const float* W_gnn = (const float*)d_in[4];
    const float* b_gnn = (const float*)d_in[5];
    const float* W1    = (const float*)d_in[6];
    const float* b1    = (const float*)d_in[7];
    const float* W2    = (const float*)d_in[8];
    const float* b2    = (const float*)d_in[9];
    const float* W3    = (const float*)d_in[10];
    const float* b3    = (const float*)d_in[11];
    const float* Wim2  = (const float*)d_in[12];
    const float* Wim3  = (const float*)d_in[13];

    const int N = in_sizes[0] / 2;
    float* h0 = (float*)d_ws;
    float* out = (float*)d_out;

    dho_h0_kernel<<<1, 64, 0, stream>>>(Xref, W1, b1, W2, b2, W3, b3, Wim2, Wim3, h0);

    const int blocks = (N + 255) / 256;
    dho_main_kernel<<<blocks, 256, 0, stream>>>(
        X, U, W1, b1, W2, b2, W3, Wim2,
        nullptr, W_fnn, W_gnn, b_gnn, b3, Wim3, Xref, h0,
        out, N);
}

// Round 2
// 246.005 us; speedup vs baseline: 1.5122x; 1.5122x over previous
//
#include <hip/hip_runtime.h>
#include <math.h>

#define HDIM 60
#define EPSC 0.01f
#define ALPHAC 0.1f

// ---------------------------------------------------------------------------
// Kernel 1: compute h_0 = ICNN(Xref) once into workspace (single tiny block).
// Runs once, not perf-critical; keeps libm precision.
// ---------------------------------------------------------------------------
__global__ void dho_h0_kernel(const float* __restrict__ Xref,
                              const float* __restrict__ W1, const float* __restrict__ b1,
                              const float* __restrict__ W2, const float* __restrict__ b2,
                              const float* __restrict__ W3, const float* __restrict__ b3,
                              const float* __restrict__ Wim2, const float* __restrict__ Wim3,
                              float* __restrict__ h0out)
{
    __shared__ float z1s[HDIM];
    __shared__ float z2s[HDIM];
    const int t = threadIdx.x;
    const float x0 = Xref[0], x1 = Xref[1];
    if (t < HDIM) {
        float a = W1[2 * t] * x0 + W1[2 * t + 1] * x1 + b1[t];
        float e = expf(-fabsf(a));
        z1s[t] = logf(1.0f + e) + fmaxf(a, 0.0f);
    }
    __syncthreads();
    if (t < HDIM) {
        float a = b2[t] + Wim2[2 * t] * x0 + Wim2[2 * t + 1] * x1;
        for (int i = 0; i < HDIM; ++i) a += W2[t * HDIM + i] * z1s[i];
        float e = expf(-fabsf(a));
        z2s[t] = logf(1.0f + e) + fmaxf(a, 0.0f);
    }
    __syncthreads();
    if (t == 0) {
        float a = b3[0] + Wim3[0] * x0 + Wim3[1] * x1;
        for (int j = 0; j < HDIM; ++j) a += W3[j] * z2s[j];
        float e = expf(-fabsf(a));
        h0out[0] = logf(1.0f + e) + fmaxf(a, 0.0f);
    }
}

// fast softplus / sigmoid helpers (v_exp_f32 / v_log_f32 / v_rcp_f32)
__device__ __forceinline__ float fast_softplus(float a, float* sig) {
    float e   = __expf(-fabsf(a));
    float inv = __builtin_amdgcn_rcpf(1.0f + e);
    *sig = (a >= 0.0f ? 1.0f : e) * inv;
    return __logf(1.0f + e) + fmaxf(a, 0.0f);
}

// ---------------------------------------------------------------------------
// Kernel 2: per-sample fused forward + analytic gradient + correction.
// One thread = one sample. NO LDS: all weights are wave-uniform and read
// directly from global in uniform control flow (n clamped, store predicated)
// so the compiler can scalarize them (s_load -> SGPR-operand v_fmac) and the
// LDS pipe never becomes the CU-shared bottleneck. W2 row is held in
// registers and serves BOTH the forward FMA (a2) and reverse-mode FMA (g1).
// __launch_bounds__(256,2): VGPR cap 256 so z1[60]+g1acc[60]+row[60] fit
// without scratch spills (R1 had VGPR=128 -> spill-inflated VALU count).
// ---------------------------------------------------------------------------
__global__ __launch_bounds__(256, 2) void dho_main_kernel(
    const float* __restrict__ X, const float* __restrict__ U,
    const float* __restrict__ W1, const float* __restrict__ b1,
    const float* __restrict__ W2, const float* __restrict__ b2,
    const float* __restrict__ W3,
    const float* __restrict__ Wim2,
    const float* __restrict__ W_fnn, const float* __restrict__ W_gnn,
    const float* __restrict__ b_gnn, const float* __restrict__ b3,
    const float* __restrict__ Wim3, const float* __restrict__ Xref,
    const float* __restrict__ h0p,
    float* __restrict__ out, int N)
{
    const int n_raw = blockIdx.x * 256 + threadIdx.x;
    const int n = n_raw < N ? n_raw : N - 1;   // clamp: keep control flow uniform

    const float2 x = ((const float2*)X)[n];
    const float  u = U[n];

    // ---- layer 1: z1 = softplus(W1 x + b1) ----
    float z1[HDIM];
#pragma unroll
    for (int i = 0; i < HDIM; ++i) {
        float a = W1[2 * i] * x.x + W1[2 * i + 1] * x.y + b1[i];
        float e = __expf(-fabsf(a));
        z1[i] = __logf(1.0f + e) + fmaxf(a, 0.0f);
    }

    // ---- layer 2 forward + reverse-mode accumulation (single pass over W2) ----
    float g1acc[HDIM];
#pragma unroll
    for (int i = 0; i < HDIM; ++i) g1acc[i] = 0.0f;

    float a3acc = 0.0f, q0 = 0.0f, q1 = 0.0f;

#pragma unroll 1
    for (int j = 0; j < HDIM; ++j) {
        const float4* rp = (const float4*)(W2 + j * HDIM);
        float4 r[15];
#pragma unroll
        for (int c = 0; c < 15; ++c) r[c] = rp[c];

        float acc0 = 0.0f, acc1 = 0.0f, acc2 = 0.0f, acc3 = 0.0f;
#pragma unroll
        for (int c = 0; c < 15; ++c) {
            acc0 += r[c].x * z1[4 * c + 0];
            acc1 += r[c].y * z1[4 * c + 1];
            acc2 += r[c].z * z1[4 * c + 2];
            acc3 += r[c].w * z1[4 * c + 3];
        }
        float wi0 = Wim2[2 * j], wi1 = Wim2[2 * j + 1];
        float a2 = (acc0 + acc1) + (acc2 + acc3) + b2[j] + wi0 * x.x + wi1 * x.y;

        float s2;
        float z2 = fast_softplus(a2, &s2);

        float w3j = W3[j];
        a3acc += w3j * z2;
        float tj = w3j * s2;
        q0 += tj * wi0;
        q1 += tj * wi1;
#pragma unroll
        for (int c = 0; c < 15; ++c) {
            g1acc[4 * c + 0] += tj * r[c].x;
            g1acc[4 * c + 1] += tj * r[c].y;
            g1acc[4 * c + 2] += tj * r[c].z;
            g1acc[4 * c + 3] += tj * r[c].w;
        }
    }

    // ---- output layer ----
    const float wim3_0 = Wim3[0], wim3_1 = Wim3[1];
    float a3 = a3acc + b3[0] + wim3_0 * x.x + wim3_1 * x.y;
    float s3;
    float hX = fast_softplus(a3, &s3);

    float h = hX - h0p[0];
    float sigma, sigp;
    if (h >= 1.0f)      { sigma = h - 0.5f;     sigp = 1.0f; }
    else if (h > 0.0f)  { sigma = 0.5f * h * h; sigp = h;    }
    else                { sigma = 0.0f;         sigp = 0.0f; }

    float dx0 = x.x - Xref[0], dx1 = x.y - Xref[1];
    float V = sigma + EPSC * (dx0 * dx0 + dx1 * dx1);

    // ---- backprop through layer 1: dh/dx = s3*(Wim3 + q + sum_i g1*s1*W1[i]) ----
    float sum0 = 0.0f, sum1 = 0.0f;
#pragma unroll
    for (int i = 0; i < HDIM; ++i) {
        float s1 = 1.0f - __expf(-z1[i]);   // sigmoid(a1) = 1 - exp(-softplus(a1))
        float c  = g1acc[i] * s1;
        sum0 += c * W1[2 * i];
        sum1 += c * W1[2 * i + 1];
    }
    float dh0 = s3 * (wim3_0 + q0 + sum0);
    float dh1 = s3 * (wim3_1 + q1 + sum1);

    float dV0 = sigp * dh0 + 2.0f * EPSC * dx0;
    float dV1 = sigp * dh1 + 2.0f * EPSC * dx1;

    // ---- dynamics + correction ----
    float f0 = W_fnn[0] * x.x + W_fnn[1] * x.y;
    float f1 = W_fnn[2] * x.x + W_fnn[3] * x.y;
    float gg0 = W_gnn[0] * x.x + W_gnn[1] * x.y + b_gnn[0];
    float gg1 = W_gnn[2] * x.x + W_gnn[3] * x.y + b_gnn[1];

    float sc = dV0 * f0 + dV1 * f1 + ALPHAC * V - fabsf(dV0 * gg0 + dV1 * gg1);
    float nrm = dV0 * dV0 + dV1 * dV1;
    float rr  = fmaxf(sc, 0.0f) * __builtin_amdgcn_rcpf(nrm);

    float o0 = f0 - dV0 * rr + gg0 * u;
    float o1 = f1 - dV1 * rr + gg1 * u;
    if (n_raw < N) ((float2*)out)[n] = make_float2(o0, o1);
}

extern "C" void kernel_launch(void* const* d_in, const int* in_sizes, int n_in,
                              void* d_out, int out_size, void* d_ws, size_t ws_size,
                              hipStream_t stream) {
    // setup_inputs order:
    // 0:X 1:U 2:Xref 3:W_fnn 4:W_gnn 5:b_gnn 6:W1 7:b1 8:W2 9:b2 10:W3 11:b3 12:Wim2 13:Wim3
    const float* X     = (const float*)d_in[0];
    const float* U     = (const float*)d_in[1];
    const float* Xref  = (const float*)d_in[2];
    const float* W_fnn = (const float*)d_in[3];
    const float* W_gnn = (const float*)d_in[4];
    const float* b_gnn = (const float*)d_in[5];
    const float* W1    = (const float*)d_in[6];
    const float* b1    = (const float*)d_in[7];
    const float* W2    = (const float*)d_in[8];
    const float* b2    = (const float*)d_in[9];
    const float* W3    = (const float*)d_in[10];
    const float* b3    = (const float*)d_in[11];
    const float* Wim2  = (const float*)d_in[12];
    const float* Wim3  = (const float*)d_in[13];

    const int N = in_sizes[0] / 2;
    float* h0 = (float*)d_ws;
    float* out = (float*)d_out;

    dho_h0_kernel<<<1, 64, 0, stream>>>(Xref, W1, b1, W2, b2, W3, b3, Wim2, Wim3, h0);

    const int blocks = (N + 255) / 256;
    dho_main_kernel<<<blocks, 256, 0, stream>>>(
        X, U, W1, b1, W2, b2, W3, Wim2,
        W_fnn, W_gnn, b_gnn, b3, Wim3, Xref, h0,
        out, N);
}